// Round 1
// baseline (18740.097 us; speedup 1.0000x reference)
//
#include <hip/hip_runtime.h>
#include <math.h>

// ---------------- problem constants ----------------
constexpr int B_ = 4, C_ = 16, O_ = 8, H_ = 192, W_ = 192;
constexpr int KS_ = 7, NL_ = 4, KJ = 125;          // KJ = MS^3
constexpr int HW_  = H_ * W_;                      // 36864
constexpr int OHW_ = O_ * HW_;                     // 294912
constexpr int COHW_ = C_ * OHW_;                   // 4718592
constexpr int NTOT = B_ * COHW_;                   // 18874368 elements
constexpr float EPS_ = 1e-5f;
constexpr float BIGF = 1e30f;

// ---------------- lift: rotated weights (double math == numpy) ----------------
__global__ void k_lift_weights(const float* __restrict__ w, float* __restrict__ wr) {
    int idx = blockIdx.x * blockDim.x + threadIdx.x;
    if (idx >= C_ * O_ * 3 * 49) return;
    int q = idx % 49;
    int i = (idx / 49) % 3;
    int o = (idx / (49 * 3)) % O_;
    int c = idx / (49 * 3 * O_);
    const double ctr = (KS_ - 1) / 2.0;
    int qy = q / KS_, qx = q % KS_;
    double ys = qy - ctr, xs = qx - ctr;
    double th = 2.0 * M_PI * (double)o / (double)O_;
    double sy = cos(th) * ys + sin(th) * xs + ctr;
    double sx = -sin(th) * ys + cos(th) * xs + ctr;
    double y0 = floor(sy), x0 = floor(sx);
    double fy = sy - y0, fx = sx - x0;
    double acc = 0.0;
    for (int dy = 0; dy < 2; dy++)
        for (int dx = 0; dx < 2; dx++) {
            int yi = (int)y0 + dy, xi = (int)x0 + dx;
            if (yi >= 0 && yi < KS_ && xi >= 0 && xi < KS_) {
                double wt = (dy ? fy : 1.0 - fy) * (dx ? fx : 1.0 - fx);
                acc += wt * (double)w[(c * 3 + i) * 49 + yi * KS_ + xi];
            }
        }
    wr[idx] = (float)acc;   // layout [c][o][i][q]
}

// ---------------- lift conv, reflect padding handled by index math ----------------
__global__ __launch_bounds__(192) void k_lift_conv(const float* __restrict__ x,
                                                   const float* __restrict__ wr,
                                                   float* __restrict__ u) {
    __shared__ float wsm[3 * 49];
    int h = blockIdx.x;
    int bco = blockIdx.y;               // b*C*O + c*O + o
    int o = bco % O_;
    int c = (bco / O_) % C_;
    int b = bco / (O_ * C_);
    const float* wp = wr + (size_t)(c * O_ + o) * 3 * 49;
    for (int t = threadIdx.x; t < 147; t += blockDim.x) wsm[t] = wp[t];
    __syncthreads();
    int wI = threadIdx.x;
    float acc = 0.f;
    for (int i = 0; i < 3; i++) {
        const float* xp = x + (size_t)(b * 3 + i) * HW_;
        for (int kh = 0; kh < 7; kh++) {
            int hy = h + kh - 3;
            hy = hy < 0 ? -hy : (hy >= H_ ? 2 * H_ - 2 - hy : hy);
            const float* xrow = xp + hy * W_;
            for (int kw = 0; kw < 7; kw++) {
                int wx = wI + kw - 3;
                wx = wx < 0 ? -wx : (wx >= W_ ? 2 * W_ - 2 - wx : wx);
                acc += wsm[i * 49 + kh * 7 + kw] * xrow[wx];
            }
        }
    }
    u[(size_t)bco * HW_ + h * W_ + wI] = acc;
}

// ---------------- batchnorm over (B,O,H,W) per channel ----------------
__global__ __launch_bounds__(256) void k_bn_reduce(const float* __restrict__ u,
                                                   float* __restrict__ sums) {
    int c = (blockIdx.x / O_) % C_;
    const float* p = u + (size_t)blockIdx.x * HW_;
    float s = 0.f, s2 = 0.f;
    for (int t = threadIdx.x; t < HW_; t += blockDim.x) {
        float v = p[t];
        s += v; s2 += v * v;
    }
    for (int off = 32; off; off >>= 1) {
        s  += __shfl_down(s, off, 64);
        s2 += __shfl_down(s2, off, 64);
    }
    __shared__ float sh[8];
    int lane = threadIdx.x & 63, wid = threadIdx.x >> 6;
    if (lane == 0) { sh[wid] = s; sh[4 + wid] = s2; }
    __syncthreads();
    if (threadIdx.x == 0) {
        s = sh[0] + sh[1] + sh[2] + sh[3];
        s2 = sh[4] + sh[5] + sh[6] + sh[7];
        atomicAdd(&sums[c], s);
        atomicAdd(&sums[C_ + c], s2);
    }
}

__global__ __launch_bounds__(256) void k_bn_apply(float* __restrict__ u,
                                                  const float* __restrict__ sums,
                                                  const float* __restrict__ gamma,
                                                  const float* __restrict__ beta) {
    int idx = blockIdx.x * blockDim.x + threadIdx.x;
    if (idx >= NTOT) return;
    int c = (idx / OHW_) % C_;
    constexpr float invN = 1.0f / (float)(B_ * O_ * HW_);
    float m = sums[c] * invN;
    float v = sums[C_ + c] * invN - m * m;
    u[idx] = (u[idx] - m) * rsqrtf(v + EPS_) * gamma[c] + beta[c];
}

// ---------------- convect: 8-tap trilinear gather (f32 geometry, clip => continuous) ----------------
__global__ __launch_bounds__(192) void k_convect(const float* __restrict__ u,
                                                 const float* __restrict__ g,
                                                 float* __restrict__ out) {
    int h = blockIdx.x;
    int bco = blockIdx.y;
    int o = bco % O_;
    int c = (bco / O_) % C_;
    int b = bco / (O_ * C_);
    float gx = g[c * 3 + 0], gy = g[c * 3 + 1], gth = g[c * 3 + 2];
    float th = ((float)(2.0 * M_PI) * (float)o) / (float)O_;
    float ct = cosf(th), st = sinf(th);
    float sx = ct * gx - st * gy;
    float sy = st * gx + ct * gy;
    float so = gth / (float)(2.0 * M_PI / (double)O_);
    float o_src = (float)o - so;
    float o0f = floorf(o_src); float fo = o_src - o0f;
    int o0 = (int)o0f;
    float ny = -sy; float y0f = floorf(ny); float fy = ny - y0f; int y0 = (int)y0f;
    float nx = -sx; float x0f = floorf(nx); float fx = nx - x0f; int x0 = (int)x0f;
    int oiA = ((o0 % O_) + O_) % O_;
    int oiB = (oiA + 1) % O_;
    const float* base = u + (size_t)(b * C_ + c) * OHW_;
    int wI = threadIdx.x;
    float acc = 0.f;
    for (int dd = 0; dd < 2; dd++) {
        float wo = dd ? fo : 1.0f - fo;
        const float* up = base + (size_t)(dd ? oiB : oiA) * HW_;
        for (int dy = 0; dy < 2; dy++) {
            int yy = h + y0 + dy;
            yy = min(max(yy, 0), H_ - 1);
            float wy = dy ? fy : 1.0f - fy;
            const float* row = up + yy * W_;
            for (int dx = 0; dx < 2; dx++) {
                int xx = wI + x0 + dx;
                xx = min(max(xx, 0), W_ - 1);
                float wgt = wo * wy * (dx ? fx : 1.0f - fx);
                acc += wgt * row[xx];
            }
        }
    }
    out[(size_t)bco * HW_ + h * W_ + wI] = acc;
}

// ---------------- morph static geometry (double math == numpy) ----------------
__global__ void k_morph_geo(int* __restrict__ dy0t, int* __restrict__ dx0t,
                            float* __restrict__ fyt, float* __restrict__ fxt,
                            int* __restrict__ dot_, float* __restrict__ c123) {
    int idx = blockIdx.x * blockDim.x + threadIdx.x;
    if (idx >= KJ * O_) return;
    int j = idx / O_, o = idx % O_;
    int dt = j / 25 - 2;
    int dy = (j / 5) % 5 - 2;
    int dx = j % 5 - 2;
    double dth = 2.0 * M_PI / (double)O_;
    double th = (double)o * dth;
    double gx = cos(th) * (double)dx - sin(th) * (double)dy;
    double gy = sin(th) * (double)dx + cos(th) * (double)dy;
    dx0t[j * O_ + o] = (int)floor(gx);
    fxt[j * O_ + o] = (float)(gx - floor(gx));
    dy0t[j * O_ + o] = (int)floor(gy);
    fyt[j * O_ + o] = (float)(gy - floor(gy));
    if (o == 0) {
        dot_[j] = dt;
        double a = (double)dt * dth;
        c123[j * 3 + 0] = (float)(cos(a / 2) * dx + sin(a / 2) * dy);
        c123[j * 3 + 1] = (float)(-sin(a / 2) * dx + cos(a / 2) * dy);
        c123[j * 3 + 2] = (float)a;
    }
}

__global__ void k_morph_kern(const float* __restrict__ wm, const float* __restrict__ c123,
                             float* __restrict__ kern, float nu_f, float eh_f) {
    int idx = blockIdx.x * blockDim.x + threadIdx.x;
    if (idx >= C_ * KJ) return;
    int c = idx / KJ, j = idx % KJ;
    float C1 = c123[j * 3 + 0], C2 = c123[j * 3 + 1], C3 = c123[j * 3 + 2];
    float rho2 = wm[c * 3 + 0] * C1 * C1 + wm[c * 3 + 1] * C2 * C2 + wm[c * 3 + 2] * C3 * C3;
    kern[c * KJ + j] = nu_f * powf(rho2, eh_f);
}

// ---------------- morph main: 125-offset scan of 4-tap bilinear, +/-BIG padding ----------------
template <int DIL>
__global__ __launch_bounds__(192) void k_morph(const float* __restrict__ u,
                                               const int* __restrict__ dy0t,
                                               const int* __restrict__ dx0t,
                                               const float* __restrict__ fyt,
                                               const float* __restrict__ fxt,
                                               const int* __restrict__ dot_,
                                               const float* __restrict__ kern,
                                               float* __restrict__ out) {
    int h = blockIdx.x;
    int bco = blockIdx.y;
    int o = bco % O_;
    int c = (bco / O_) % C_;
    int b = bco / (O_ * C_);
    __shared__ int s_oi[KJ], s_iy[KJ], s_ix[KJ];
    __shared__ float s_fy[KJ], s_fx[KJ], s_k[KJ];
    for (int t = threadIdx.x; t < KJ; t += blockDim.x) {
        int d = dot_[t];
        int oi = ((o + d) % O_ + O_) % O_;
        s_oi[t] = oi;
        s_iy[t] = dy0t[t * O_ + o];
        s_ix[t] = dx0t[t * O_ + o];
        s_fy[t] = fyt[t * O_ + o];
        s_fx[t] = fxt[t * O_ + o];
        s_k[t] = kern[c * KJ + t];
    }
    __syncthreads();
    int wI = threadIdx.x;
    const float PV = DIL ? -BIGF : BIGF;
    float acc = PV;
    const float* base = u + (size_t)(b * C_ + c) * OHW_;
    for (int j = 0; j < KJ; j++) {
        const float* up = base + (size_t)s_oi[j] * HW_;
        int iy = h + s_iy[j];
        int ix = wI + s_ix[j];
        float fy = s_fy[j], fx = s_fx[j];
        float val = 0.f;
        for (int a2 = 0; a2 < 2; a2++) {
            int yy = iy + a2;
            float wy = a2 ? fy : 1.0f - fy;
            bool yin = (yy >= 0 && yy < H_);
            const float* row = up + yy * W_;
            for (int b2 = 0; b2 < 2; b2++) {
                int xx = ix + b2;
                float wgt = wy * (b2 ? fx : 1.0f - fx);
                float v = (yin && xx >= 0 && xx < W_) ? row[xx] : PV;
                val += wgt * v;
            }
        }
        if (DIL) acc = fmaxf(acc, val - s_k[j]);
        else     acc = fminf(acc, val + s_k[j]);
    }
    out[(size_t)bco * HW_ + h * W_ + wI] = acc;
}

// ---------------- channel linear: z[b,d,o,h,w] = sum_c lin[d,c]*cat(d,e) ----------------
__global__ __launch_bounds__(256) void k_linear(const float* __restrict__ dbuf,
                                                const float* __restrict__ ebuf,
                                                const float* __restrict__ lin,
                                                float* __restrict__ out) {
    __shared__ float lsm[C_ * 2 * C_];
    for (int t = threadIdx.x; t < C_ * 2 * C_; t += blockDim.x) lsm[t] = lin[t];
    __syncthreads();
    int idx = blockIdx.x * blockDim.x + threadIdx.x;   // over B*O*H*W
    if (idx >= B_ * OHW_) return;
    int pos = idx % OHW_;
    int b = idx / OHW_;
    const float* dp = dbuf + (size_t)b * COHW_ + pos;
    const float* ep = ebuf + (size_t)b * COHW_ + pos;
    float vin[2 * C_];
    for (int c2 = 0; c2 < C_; c2++) {
        vin[c2] = dp[(size_t)c2 * OHW_];
        vin[C_ + c2] = ep[(size_t)c2 * OHW_];
    }
    for (int dch = 0; dch < C_; dch++) {
        float s = 0.f;
        for (int c2 = 0; c2 < 2 * C_; c2++) s += lsm[dch * 2 * C_ + c2] * vin[c2];
        out[(size_t)b * COHW_ + (size_t)dch * OHW_ + pos] = s;
    }
}

// ---------------- final: max over O, project, sigmoid ----------------
__global__ __launch_bounds__(256) void k_final(const float* __restrict__ u,
                                               const float* __restrict__ fw,
                                               float* __restrict__ out) {
    int idx = blockIdx.x * blockDim.x + threadIdx.x;   // B*H*W
    if (idx >= B_ * HW_) return;
    int pos = idx % HW_;
    int b = idx / HW_;
    const float* up = u + (size_t)b * COHW_ + pos;
    float y = 0.f;
    for (int c2 = 0; c2 < C_; c2++) {
        float m = up[(size_t)(c2 * O_) * HW_];
        for (int o2 = 1; o2 < O_; o2++) m = fmaxf(m, up[(size_t)(c2 * O_ + o2) * HW_]);
        y += fw[c2] * m;
    }
    out[idx] = 1.0f / (1.0f + expf(-y));
}

// ---------------- host orchestration ----------------
extern "C" void kernel_launch(void* const* d_in, const int* in_sizes, int n_in,
                              void* d_out, int out_size, void* d_ws, size_t ws_size,
                              hipStream_t stream) {
    const float* x          = (const float*)d_in[0];
    const float* lift_w     = (const float*)d_in[1];
    const float* lift_gamma = (const float*)d_in[2];
    const float* lift_beta  = (const float*)d_in[3];
    const float* pde_g      = (const float*)d_in[4];
    const float* pde_metric = (const float*)d_in[5];
    const float* pde_lin    = (const float*)d_in[6];
    const float* pde_gamma  = (const float*)d_in[7];
    const float* pde_beta   = (const float*)d_in[8];
    const float* final_w    = (const float*)d_in[9];
    float* out = (float*)d_out;

    float* ws   = (float*)d_ws;
    float* bufA = ws;                         // u
    float* bufB = ws + (size_t)NTOT;          // scratch (convect out / z)
    float* bufC = ws + 2 * (size_t)NTOT;      // d
    float* wr   = ws + 3 * (size_t)NTOT;      // 18816
    float* fyt  = wr + 18816;                 // 1000
    float* fxt  = fyt + 1000;                 // 1000
    float* c123 = fxt + 1000;                 // 375
    float* kern = c123 + 375;                 // 2000
    float* sums = kern + 2000;                // 32
    int* dy0t = (int*)(sums + 32);            // 1000
    int* dx0t = dy0t + 1000;                  // 1000
    int* dot_ = dx0t + 1000;                  // 125

    const double ALPHA = 0.65;
    const double EXPO = 2.0 * ALPHA / (2.0 * ALPHA - 1.0);
    const double NU = (2.0 * ALPHA - 1.0) * pow(2.0 * ALPHA, -EXPO);
    const float nu_f = (float)NU;
    const float eh_f = (float)(EXPO / 2.0);

    dim3 rowGrid(H_, B_ * C_ * O_);

    k_lift_weights<<<(C_ * O_ * 3 * 49 + 255) / 256, 256, 0, stream>>>(lift_w, wr);
    k_morph_geo<<<(KJ * O_ + 255) / 256, 256, 0, stream>>>(dy0t, dx0t, fyt, fxt, dot_, c123);
    k_lift_conv<<<rowGrid, 192, 0, stream>>>(x, wr, bufA);

    hipMemsetAsync(sums, 0, 2 * C_ * sizeof(float), stream);
    k_bn_reduce<<<B_ * C_ * O_, 256, 0, stream>>>(bufA, sums);
    k_bn_apply<<<(NTOT + 255) / 256, 256, 0, stream>>>(bufA, sums, lift_gamma, lift_beta);

    for (int l = 0; l < NL_; l++) {
        const float* g0 = pde_g + (size_t)(l * 2 + 0) * C_ * 3;
        const float* g1 = pde_g + (size_t)(l * 2 + 1) * C_ * 3;
        const float* m0 = pde_metric + (size_t)(l * 2 + 0) * C_ * 3;
        const float* m1 = pde_metric + (size_t)(l * 2 + 1) * C_ * 3;
        const float* lin = pde_lin + (size_t)l * C_ * 2 * C_;
        const float* ga = pde_gamma + l * C_;
        const float* be = pde_beta + l * C_;

        // d = morph_dilate(convect(u,g0))
        k_convect<<<rowGrid, 192, 0, stream>>>(bufA, g0, bufB);
        k_morph_kern<<<(C_ * KJ + 255) / 256, 256, 0, stream>>>(m0, c123, kern, nu_f, eh_f);
        k_morph<1><<<rowGrid, 192, 0, stream>>>(bufB, dy0t, dx0t, fyt, fxt, dot_, kern, bufC);
        // e = morph_erode(convect(u,g1))  -- e overwrites u (dead after this convect)
        k_convect<<<rowGrid, 192, 0, stream>>>(bufA, g1, bufB);
        k_morph_kern<<<(C_ * KJ + 255) / 256, 256, 0, stream>>>(m1, c123, kern, nu_f, eh_f);
        k_morph<0><<<rowGrid, 192, 0, stream>>>(bufB, dy0t, dx0t, fyt, fxt, dot_, kern, bufA);
        // z = lin * cat(d,e) -> bufB ; bn(z)
        k_linear<<<(B_ * OHW_ + 255) / 256, 256, 0, stream>>>(bufC, bufA, lin, bufB);
        hipMemsetAsync(sums, 0, 2 * C_ * sizeof(float), stream);
        k_bn_reduce<<<B_ * C_ * O_, 256, 0, stream>>>(bufB, sums);
        k_bn_apply<<<(NTOT + 255) / 256, 256, 0, stream>>>(bufB, sums, ga, be);
        // rotate: new u = bufB
        float* t = bufA; bufA = bufB; bufB = t;
    }

    k_final<<<(B_ * HW_ + 255) / 256, 256, 0, stream>>>(bufA, final_w, out);
}

// Round 4
// 12201.582 us; speedup vs baseline: 1.5359x; 1.5359x over previous
//
#include <hip/hip_runtime.h>
#include <math.h>

// ---------------- problem constants ----------------
constexpr int B_ = 4, C_ = 16, O_ = 8, H_ = 192, W_ = 192;
constexpr int KS_ = 7, NL_ = 4, KJ = 125;          // KJ = MS^3
constexpr int HW_  = H_ * W_;                      // 36864
constexpr int OHW_ = O_ * HW_;                     // 294912
constexpr int COHW_ = C_ * OHW_;                   // 4718592
constexpr int NTOT = B_ * COHW_;                   // 18874368 elements
constexpr float EPS_ = 1e-5f;
constexpr float BIGF = 1e30f;
constexpr int NPLANES = B_ * C_ * O_;              // 512
constexpr int ROWS = 4;                            // output rows per thread in k_morph

// ---------------- lift: rotated weights (double math == numpy) ----------------
__global__ void k_lift_weights(const float* __restrict__ w, float* __restrict__ wr) {
    int idx = blockIdx.x * blockDim.x + threadIdx.x;
    if (idx >= C_ * O_ * 3 * 49) return;
    int q = idx % 49;
    int i = (idx / 49) % 3;
    int o = (idx / (49 * 3)) % O_;
    int c = idx / (49 * 3 * O_);
    const double ctr = (KS_ - 1) / 2.0;
    int qy = q / KS_, qx = q % KS_;
    double ys = qy - ctr, xs = qx - ctr;
    double th = 2.0 * M_PI * (double)o / (double)O_;
    double sy = cos(th) * ys + sin(th) * xs + ctr;
    double sx = -sin(th) * ys + cos(th) * xs + ctr;
    double y0 = floor(sy), x0 = floor(sx);
    double fy = sy - y0, fx = sx - x0;
    double acc = 0.0;
    for (int dy = 0; dy < 2; dy++)
        for (int dx = 0; dx < 2; dx++) {
            int yi = (int)y0 + dy, xi = (int)x0 + dx;
            if (yi >= 0 && yi < KS_ && xi >= 0 && xi < KS_) {
                double wt = (dy ? fy : 1.0 - fy) * (dx ? fx : 1.0 - fx);
                acc += wt * (double)w[(c * 3 + i) * 49 + yi * KS_ + xi];
            }
        }
    wr[idx] = (float)acc;   // layout [c][o][i][q]
}

// ---------------- lift conv, reflect padding handled by index math ----------------
__global__ __launch_bounds__(192) void k_lift_conv(const float* __restrict__ x,
                                                   const float* __restrict__ wr,
                                                   float* __restrict__ u) {
    __shared__ float wsm[3 * 49];
    int h = blockIdx.x;
    int bco = blockIdx.y;               // b*C*O + c*O + o
    int o = bco % O_;
    int c = (bco / O_) % C_;
    int b = bco / (O_ * C_);
    const float* wp = wr + (size_t)(c * O_ + o) * 3 * 49;
    for (int t = threadIdx.x; t < 147; t += blockDim.x) wsm[t] = wp[t];
    __syncthreads();
    int wI = threadIdx.x;
    float acc = 0.f;
    for (int i = 0; i < 3; i++) {
        const float* xp = x + (size_t)(b * 3 + i) * HW_;
        for (int kh = 0; kh < 7; kh++) {
            int hy = h + kh - 3;
            hy = hy < 0 ? -hy : (hy >= H_ ? 2 * H_ - 2 - hy : hy);
            const float* xrow = xp + hy * W_;
            for (int kw = 0; kw < 7; kw++) {
                int wx = wI + kw - 3;
                wx = wx < 0 ? -wx : (wx >= W_ ? 2 * W_ - 2 - wx : wx);
                acc += wsm[i * 49 + kh * 7 + kw] * xrow[wx];
            }
        }
    }
    u[(size_t)bco * HW_ + h * W_ + wI] = acc;
}

// ---------------- batchnorm over (B,O,H,W) per channel ----------------
__global__ __launch_bounds__(256) void k_bn_reduce(const float* __restrict__ u,
                                                   float* __restrict__ sums) {
    int c = (blockIdx.x / O_) % C_;
    const float* p = u + (size_t)blockIdx.x * HW_;
    float s = 0.f, s2 = 0.f;
    for (int t = threadIdx.x; t < HW_; t += blockDim.x) {
        float v = p[t];
        s += v; s2 += v * v;
    }
    for (int off = 32; off; off >>= 1) {
        s  += __shfl_down(s, off, 64);
        s2 += __shfl_down(s2, off, 64);
    }
    __shared__ float sh[8];
    int lane = threadIdx.x & 63, wid = threadIdx.x >> 6;
    if (lane == 0) { sh[wid] = s; sh[4 + wid] = s2; }
    __syncthreads();
    if (threadIdx.x == 0) {
        s = sh[0] + sh[1] + sh[2] + sh[3];
        s2 = sh[4] + sh[5] + sh[6] + sh[7];
        atomicAdd(&sums[c], s);
        atomicAdd(&sums[C_ + c], s2);
    }
}

__global__ __launch_bounds__(256) void k_bn_apply(float* __restrict__ u,
                                                  const float* __restrict__ sums,
                                                  const float* __restrict__ gamma,
                                                  const float* __restrict__ beta) {
    int idx = blockIdx.x * blockDim.x + threadIdx.x;
    if (idx >= NTOT) return;
    int c = (idx / OHW_) % C_;
    constexpr float invN = 1.0f / (float)(B_ * O_ * HW_);
    float m = sums[c] * invN;
    float v = sums[C_ + c] * invN - m * m;
    u[idx] = (u[idx] - m) * rsqrtf(v + EPS_) * gamma[c] + beta[c];
}

// ---------------- convect: 8-tap trilinear gather (f32 geometry, clip => continuous) ----------------
__global__ __launch_bounds__(192) void k_convect(const float* __restrict__ u,
                                                 const float* __restrict__ g,
                                                 float* __restrict__ out) {
    int h = blockIdx.x;
    int bco = blockIdx.y;
    int o = bco % O_;
    int c = (bco / O_) % C_;
    int b = bco / (O_ * C_);
    float gx = g[c * 3 + 0], gy = g[c * 3 + 1], gth = g[c * 3 + 2];
    float th = ((float)(2.0 * M_PI) * (float)o) / (float)O_;
    float ct = cosf(th), st = sinf(th);
    float sx = ct * gx - st * gy;
    float sy = st * gx + ct * gy;
    float so = gth / (float)(2.0 * M_PI / (double)O_);
    float o_src = (float)o - so;
    float o0f = floorf(o_src); float fo = o_src - o0f;
    int o0 = (int)o0f;
    float ny = -sy; float y0f = floorf(ny); float fy = ny - y0f; int y0 = (int)y0f;
    float nx = -sx; float x0f = floorf(nx); float fx = nx - x0f; int x0 = (int)x0f;
    int oiA = ((o0 % O_) + O_) % O_;
    int oiB = (oiA + 1) % O_;
    const float* base = u + (size_t)(b * C_ + c) * OHW_;
    int wI = threadIdx.x;
    float acc = 0.f;
    for (int dd = 0; dd < 2; dd++) {
        float wo = dd ? fo : 1.0f - fo;
        const float* up = base + (size_t)(dd ? oiB : oiA) * HW_;
        for (int dy = 0; dy < 2; dy++) {
            int yy = h + y0 + dy;
            yy = min(max(yy, 0), H_ - 1);
            float wy = dy ? fy : 1.0f - fy;
            const float* row = up + yy * W_;
            for (int dx = 0; dx < 2; dx++) {
                int xx = wI + x0 + dx;
                xx = min(max(xx, 0), W_ - 1);
                float wgt = wo * wy * (dx ? fx : 1.0f - fx);
                acc += wgt * row[xx];
            }
        }
    }
    out[(size_t)bco * HW_ + h * W_ + wI] = acc;
}

// ---------------- morph static geometry (double math == numpy) ----------------
__global__ void k_morph_geo(int* __restrict__ dy0t, int* __restrict__ dx0t,
                            float* __restrict__ fyt, float* __restrict__ fxt,
                            int* __restrict__ dot_, float* __restrict__ c123) {
    int idx = blockIdx.x * blockDim.x + threadIdx.x;
    if (idx >= KJ * O_) return;
    int j = idx / O_, o = idx % O_;
    int dt = j / 25 - 2;
    int dy = (j / 5) % 5 - 2;
    int dx = j % 5 - 2;
    double dth = 2.0 * M_PI / (double)O_;
    double th = (double)o * dth;
    double gx = cos(th) * (double)dx - sin(th) * (double)dy;
    double gy = sin(th) * (double)dx + cos(th) * (double)dy;
    dx0t[j * O_ + o] = (int)floor(gx);
    fxt[j * O_ + o] = (float)(gx - floor(gx));
    dy0t[j * O_ + o] = (int)floor(gy);
    fyt[j * O_ + o] = (float)(gy - floor(gy));
    if (o == 0) {
        dot_[j] = dt;
        double a = (double)dt * dth;
        c123[j * 3 + 0] = (float)(cos(a / 2) * dx + sin(a / 2) * dy);
        c123[j * 3 + 1] = (float)(-sin(a / 2) * dx + cos(a / 2) * dy);
        c123[j * 3 + 2] = (float)a;
    }
}

__global__ void k_morph_kern(const float* __restrict__ wm, const float* __restrict__ c123,
                             float* __restrict__ kern, float nu_f, float eh_f) {
    int idx = blockIdx.x * blockDim.x + threadIdx.x;
    if (idx >= C_ * KJ) return;
    int c = idx / KJ, j = idx % KJ;
    float C1 = c123[j * 3 + 0], C2 = c123[j * 3 + 1], C3 = c123[j * 3 + 2];
    float rho2 = wm[c * 3 + 0] * C1 * C1 + wm[c * 3 + 1] * C2 * C2 + wm[c * 3 + 2] * C3 * C3;
    kern[c * KJ + j] = nu_f * powf(rho2, eh_f);
}

// ---------------- morph main: R0-verbatim inner body, ROWS output rows per thread ----------------
template <int DIL>
__global__ __launch_bounds__(192) void k_morph(const float* __restrict__ u,
                                               const int* __restrict__ dy0t,
                                               const int* __restrict__ dx0t,
                                               const float* __restrict__ fyt,
                                               const float* __restrict__ fxt,
                                               const int* __restrict__ dot_,
                                               const float* __restrict__ kern,
                                               float* __restrict__ out) {
    int h0 = blockIdx.x * ROWS;
    int bco = blockIdx.y;
    int o = bco % O_;
    int c = (bco / O_) % C_;
    int b = bco / (O_ * C_);
    __shared__ int s_oi[KJ], s_iy[KJ], s_ix[KJ];
    __shared__ float s_fy[KJ], s_fx[KJ], s_k[KJ];
    for (int t = threadIdx.x; t < KJ; t += blockDim.x) {
        int d = dot_[t];
        int oi = ((o + d) % O_ + O_) % O_;
        s_oi[t] = oi;
        s_iy[t] = dy0t[t * O_ + o];
        s_ix[t] = dx0t[t * O_ + o];
        s_fy[t] = fyt[t * O_ + o];
        s_fx[t] = fxt[t * O_ + o];
        s_k[t] = kern[c * KJ + t];
    }
    __syncthreads();
    int wI = threadIdx.x;
    const float PV = DIL ? -BIGF : BIGF;
    float acc[ROWS];
#pragma unroll
    for (int r = 0; r < ROWS; r++) acc[r] = PV;
    const float* base = u + (size_t)(b * C_ + c) * OHW_;
    for (int j = 0; j < KJ; j++) {
        const float* up = base + (size_t)s_oi[j] * HW_;
        int ix = wI + s_ix[j];
        float fy = s_fy[j], fx = s_fx[j], kk = s_k[j];
#pragma unroll
        for (int r = 0; r < ROWS; r++) {
            int iy = h0 + r + s_iy[j];
            float val = 0.f;
#pragma unroll
            for (int a2 = 0; a2 < 2; a2++) {
                int yy = iy + a2;
                float wy = a2 ? fy : 1.0f - fy;
                bool yin = (yy >= 0 && yy < H_);
                const float* row = up + yy * W_;
#pragma unroll
                for (int b2 = 0; b2 < 2; b2++) {
                    int xx = ix + b2;
                    float wgt = wy * (b2 ? fx : 1.0f - fx);
                    float v = (yin && xx >= 0 && xx < W_) ? row[xx] : PV;
                    val += wgt * v;
                }
            }
            if (DIL) acc[r] = fmaxf(acc[r], val - kk);
            else     acc[r] = fminf(acc[r], val + kk);
        }
    }
    float* op = out + (size_t)bco * HW_ + (size_t)h0 * W_ + wI;
#pragma unroll
    for (int r = 0; r < ROWS; r++) op[r * W_] = acc[r];
}

// ---------------- channel linear: z[b,d,o,h,w] = sum_c lin[d,c]*cat(d,e) ----------------
__global__ __launch_bounds__(256) void k_linear(const float* __restrict__ dbuf,
                                                const float* __restrict__ ebuf,
                                                const float* __restrict__ lin,
                                                float* __restrict__ out) {
    __shared__ float lsm[C_ * 2 * C_];
    for (int t = threadIdx.x; t < C_ * 2 * C_; t += blockDim.x) lsm[t] = lin[t];
    __syncthreads();
    int idx = blockIdx.x * blockDim.x + threadIdx.x;   // over B*O*H*W
    if (idx >= B_ * OHW_) return;
    int pos = idx % OHW_;
    int b = idx / OHW_;
    const float* dp = dbuf + (size_t)b * COHW_ + pos;
    const float* ep = ebuf + (size_t)b * COHW_ + pos;
    float vin[2 * C_];
    for (int c2 = 0; c2 < C_; c2++) {
        vin[c2] = dp[(size_t)c2 * OHW_];
        vin[C_ + c2] = ep[(size_t)c2 * OHW_];
    }
    for (int dch = 0; dch < C_; dch++) {
        float s = 0.f;
        for (int c2 = 0; c2 < 2 * C_; c2++) s += lsm[dch * 2 * C_ + c2] * vin[c2];
        out[(size_t)b * COHW_ + (size_t)dch * OHW_ + pos] = s;
    }
}

// ---------------- final: max over O, project, sigmoid ----------------
__global__ __launch_bounds__(256) void k_final(const float* __restrict__ u,
                                               const float* __restrict__ fw,
                                               float* __restrict__ out) {
    int idx = blockIdx.x * blockDim.x + threadIdx.x;   // B*H*W
    if (idx >= B_ * HW_) return;
    int pos = idx % HW_;
    int b = idx / HW_;
    const float* up = u + (size_t)b * COHW_ + pos;
    float y = 0.f;
    for (int c2 = 0; c2 < C_; c2++) {
        float m = up[(size_t)(c2 * O_) * HW_];
        for (int o2 = 1; o2 < O_; o2++) m = fmaxf(m, up[(size_t)(c2 * O_ + o2) * HW_]);
        y += fw[c2] * m;
    }
    out[idx] = 1.0f / (1.0f + expf(-y));
}

// ---------------- host orchestration ----------------
extern "C" void kernel_launch(void* const* d_in, const int* in_sizes, int n_in,
                              void* d_out, int out_size, void* d_ws, size_t ws_size,
                              hipStream_t stream) {
    const float* x          = (const float*)d_in[0];
    const float* lift_w     = (const float*)d_in[1];
    const float* lift_gamma = (const float*)d_in[2];
    const float* lift_beta  = (const float*)d_in[3];
    const float* pde_g      = (const float*)d_in[4];
    const float* pde_metric = (const float*)d_in[5];
    const float* pde_lin    = (const float*)d_in[6];
    const float* pde_gamma  = (const float*)d_in[7];
    const float* pde_beta   = (const float*)d_in[8];
    const float* final_w    = (const float*)d_in[9];
    float* out = (float*)d_out;

    float* ws   = (float*)d_ws;
    float* bufA = ws;                         // u
    float* bufB = ws + (size_t)NTOT;          // scratch (convect out / z)
    float* bufC = ws + 2 * (size_t)NTOT;      // d
    float* wr   = ws + 3 * (size_t)NTOT;      // 18816
    float* fyt  = wr + 18816;                 // 1000
    float* fxt  = fyt + 1000;                 // 1000
    float* c123 = fxt + 1000;                 // 375
    float* kern = c123 + 375;                 // 2000
    float* sums = kern + 2000;                // 32
    int* dy0t = (int*)(sums + 32);            // 1000
    int* dx0t = dy0t + 1000;                  // 1000
    int* dot_ = dx0t + 1000;                  // 125

    const double ALPHA = 0.65;
    const double EXPO = 2.0 * ALPHA / (2.0 * ALPHA - 1.0);
    const double NU = (2.0 * ALPHA - 1.0) * pow(2.0 * ALPHA, -EXPO);
    const float nu_f = (float)NU;
    const float eh_f = (float)(EXPO / 2.0);

    dim3 rowGrid(H_, B_ * C_ * O_);
    dim3 morphGrid(H_ / ROWS, B_ * C_ * O_);

    k_lift_weights<<<(C_ * O_ * 3 * 49 + 255) / 256, 256, 0, stream>>>(lift_w, wr);
    k_morph_geo<<<(KJ * O_ + 255) / 256, 256, 0, stream>>>(dy0t, dx0t, fyt, fxt, dot_, c123);
    k_lift_conv<<<rowGrid, 192, 0, stream>>>(x, wr, bufA);

    hipMemsetAsync(sums, 0, 2 * C_ * sizeof(float), stream);
    k_bn_reduce<<<B_ * C_ * O_, 256, 0, stream>>>(bufA, sums);
    k_bn_apply<<<(NTOT + 255) / 256, 256, 0, stream>>>(bufA, sums, lift_gamma, lift_beta);

    for (int l = 0; l < NL_; l++) {
        const float* g0 = pde_g + (size_t)(l * 2 + 0) * C_ * 3;
        const float* g1 = pde_g + (size_t)(l * 2 + 1) * C_ * 3;
        const float* m0 = pde_metric + (size_t)(l * 2 + 0) * C_ * 3;
        const float* m1 = pde_metric + (size_t)(l * 2 + 1) * C_ * 3;
        const float* lin = pde_lin + (size_t)l * C_ * 2 * C_;
        const float* ga = pde_gamma + l * C_;
        const float* be = pde_beta + l * C_;

        // d = morph_dilate(convect(u,g0))
        k_convect<<<rowGrid, 192, 0, stream>>>(bufA, g0, bufB);
        k_morph_kern<<<(C_ * KJ + 255) / 256, 256, 0, stream>>>(m0, c123, kern, nu_f, eh_f);
        k_morph<1><<<morphGrid, 192, 0, stream>>>(bufB, dy0t, dx0t, fyt, fxt, dot_, kern, bufC);
        // e = morph_erode(convect(u,g1))  -- e overwrites u (dead after this convect)
        k_convect<<<rowGrid, 192, 0, stream>>>(bufA, g1, bufB);
        k_morph_kern<<<(C_ * KJ + 255) / 256, 256, 0, stream>>>(m1, c123, kern, nu_f, eh_f);
        k_morph<0><<<morphGrid, 192, 0, stream>>>(bufB, dy0t, dx0t, fyt, fxt, dot_, kern, bufA);
        // z = lin * cat(d,e) -> bufB ; bn(z)
        k_linear<<<(B_ * OHW_ + 255) / 256, 256, 0, stream>>>(bufC, bufA, lin, bufB);
        hipMemsetAsync(sums, 0, 2 * C_ * sizeof(float), stream);
        k_bn_reduce<<<B_ * C_ * O_, 256, 0, stream>>>(bufB, sums);
        k_bn_apply<<<(NTOT + 255) / 256, 256, 0, stream>>>(bufB, sums, ga, be);
        // rotate: new u = bufB
        float* t = bufA; bufA = bufB; bufB = t;
    }

    k_final<<<(B_ * HW_ + 255) / 256, 256, 0, stream>>>(bufA, final_w, out);
}

// Round 5
// 10416.478 us; speedup vs baseline: 1.7991x; 1.1714x over previous
//
#include <hip/hip_runtime.h>
#include <math.h>

// ---------------- problem constants ----------------
constexpr int B_ = 4, C_ = 16, O_ = 8, H_ = 192, W_ = 192;
constexpr int KS_ = 7, NL_ = 4, KJ = 125;          // KJ = MS^3
constexpr int HW_  = H_ * W_;                      // 36864
constexpr int OHW_ = O_ * HW_;                     // 294912
constexpr int COHW_ = C_ * OHW_;                   // 4718592
constexpr int NTOT = B_ * COHW_;                   // 18874368 elements
constexpr float EPS_ = 1e-5f;
constexpr float BIGF = 1e30f;
constexpr int NPLANES = B_ * C_ * O_;              // 512
constexpr int ROWS = 4;                            // output rows per thread in k_morph

// ---------------- lift: rotated weights (double math == numpy) ----------------
__global__ void k_lift_weights(const float* __restrict__ w, float* __restrict__ wr) {
    int idx = blockIdx.x * blockDim.x + threadIdx.x;
    if (idx >= C_ * O_ * 3 * 49) return;
    int q = idx % 49;
    int i = (idx / 49) % 3;
    int o = (idx / (49 * 3)) % O_;
    int c = idx / (49 * 3 * O_);
    const double ctr = (KS_ - 1) / 2.0;
    int qy = q / KS_, qx = q % KS_;
    double ys = qy - ctr, xs = qx - ctr;
    double th = 2.0 * M_PI * (double)o / (double)O_;
    double sy = cos(th) * ys + sin(th) * xs + ctr;
    double sx = -sin(th) * ys + cos(th) * xs + ctr;
    double y0 = floor(sy), x0 = floor(sx);
    double fy = sy - y0, fx = sx - x0;
    double acc = 0.0;
    for (int dy = 0; dy < 2; dy++)
        for (int dx = 0; dx < 2; dx++) {
            int yi = (int)y0 + dy, xi = (int)x0 + dx;
            if (yi >= 0 && yi < KS_ && xi >= 0 && xi < KS_) {
                double wt = (dy ? fy : 1.0 - fy) * (dx ? fx : 1.0 - fx);
                acc += wt * (double)w[(c * 3 + i) * 49 + yi * KS_ + xi];
            }
        }
    wr[idx] = (float)acc;   // layout [c][o][i][q]
}

// ---------------- lift conv, reflect padding handled by index math ----------------
__global__ __launch_bounds__(192) void k_lift_conv(const float* __restrict__ x,
                                                   const float* __restrict__ wr,
                                                   float* __restrict__ u) {
    __shared__ float wsm[3 * 49];
    int h = blockIdx.x;
    int bco = blockIdx.y;               // b*C*O + c*O + o
    int o = bco % O_;
    int c = (bco / O_) % C_;
    int b = bco / (O_ * C_);
    const float* wp = wr + (size_t)(c * O_ + o) * 3 * 49;
    for (int t = threadIdx.x; t < 147; t += blockDim.x) wsm[t] = wp[t];
    __syncthreads();
    int wI = threadIdx.x;
    float acc = 0.f;
    for (int i = 0; i < 3; i++) {
        const float* xp = x + (size_t)(b * 3 + i) * HW_;
        for (int kh = 0; kh < 7; kh++) {
            int hy = h + kh - 3;
            hy = hy < 0 ? -hy : (hy >= H_ ? 2 * H_ - 2 - hy : hy);
            const float* xrow = xp + hy * W_;
            for (int kw = 0; kw < 7; kw++) {
                int wx = wI + kw - 3;
                wx = wx < 0 ? -wx : (wx >= W_ ? 2 * W_ - 2 - wx : wx);
                acc += wsm[i * 49 + kh * 7 + kw] * xrow[wx];
            }
        }
    }
    u[(size_t)bco * HW_ + h * W_ + wI] = acc;
}

// ---------------- batchnorm over (B,O,H,W) per channel ----------------
__global__ __launch_bounds__(256) void k_bn_reduce(const float* __restrict__ u,
                                                   float* __restrict__ sums) {
    int c = (blockIdx.x / O_) % C_;
    const float* p = u + (size_t)blockIdx.x * HW_;
    float s = 0.f, s2 = 0.f;
    for (int t = threadIdx.x; t < HW_; t += blockDim.x) {
        float v = p[t];
        s += v; s2 += v * v;
    }
    for (int off = 32; off; off >>= 1) {
        s  += __shfl_down(s, off, 64);
        s2 += __shfl_down(s2, off, 64);
    }
    __shared__ float sh[8];
    int lane = threadIdx.x & 63, wid = threadIdx.x >> 6;
    if (lane == 0) { sh[wid] = s; sh[4 + wid] = s2; }
    __syncthreads();
    if (threadIdx.x == 0) {
        s = sh[0] + sh[1] + sh[2] + sh[3];
        s2 = sh[4] + sh[5] + sh[6] + sh[7];
        atomicAdd(&sums[c], s);
        atomicAdd(&sums[C_ + c], s2);
    }
}

__global__ __launch_bounds__(256) void k_bn_apply(float* __restrict__ u,
                                                  const float* __restrict__ sums,
                                                  const float* __restrict__ gamma,
                                                  const float* __restrict__ beta) {
    int idx = blockIdx.x * blockDim.x + threadIdx.x;
    if (idx >= NTOT) return;
    int c = (idx / OHW_) % C_;
    constexpr float invN = 1.0f / (float)(B_ * O_ * HW_);
    float m = sums[c] * invN;
    float v = sums[C_ + c] * invN - m * m;
    u[idx] = (u[idx] - m) * rsqrtf(v + EPS_) * gamma[c] + beta[c];
}

// ---------------- convect: 8-tap trilinear gather (f32 geometry, clip => continuous) ----------------
__global__ __launch_bounds__(192) void k_convect(const float* __restrict__ u,
                                                 const float* __restrict__ g,
                                                 float* __restrict__ out) {
    int h = blockIdx.x;
    int bco = blockIdx.y;
    int o = bco % O_;
    int c = (bco / O_) % C_;
    int b = bco / (O_ * C_);
    float gx = g[c * 3 + 0], gy = g[c * 3 + 1], gth = g[c * 3 + 2];
    float th = ((float)(2.0 * M_PI) * (float)o) / (float)O_;
    float ct = cosf(th), st = sinf(th);
    float sx = ct * gx - st * gy;
    float sy = st * gx + ct * gy;
    float so = gth / (float)(2.0 * M_PI / (double)O_);
    float o_src = (float)o - so;
    float o0f = floorf(o_src); float fo = o_src - o0f;
    int o0 = (int)o0f;
    float ny = -sy; float y0f = floorf(ny); float fy = ny - y0f; int y0 = (int)y0f;
    float nx = -sx; float x0f = floorf(nx); float fx = nx - x0f; int x0 = (int)x0f;
    int oiA = ((o0 % O_) + O_) % O_;
    int oiB = (oiA + 1) % O_;
    const float* base = u + (size_t)(b * C_ + c) * OHW_;
    int wI = threadIdx.x;
    float acc = 0.f;
    for (int dd = 0; dd < 2; dd++) {
        float wo = dd ? fo : 1.0f - fo;
        const float* up = base + (size_t)(dd ? oiB : oiA) * HW_;
        for (int dy = 0; dy < 2; dy++) {
            int yy = h + y0 + dy;
            yy = min(max(yy, 0), H_ - 1);
            float wy = dy ? fy : 1.0f - fy;
            const float* row = up + yy * W_;
            for (int dx = 0; dx < 2; dx++) {
                int xx = wI + x0 + dx;
                xx = min(max(xx, 0), W_ - 1);
                float wgt = wo * wy * (dx ? fx : 1.0f - fx);
                acc += wgt * row[xx];
            }
        }
    }
    out[(size_t)bco * HW_ + h * W_ + wI] = acc;
}

// ---------------- morph static geometry (double math == numpy) ----------------
__global__ void k_morph_geo(int* __restrict__ dy0t, int* __restrict__ dx0t,
                            float* __restrict__ fyt, float* __restrict__ fxt,
                            int* __restrict__ dot_, float* __restrict__ c123) {
    int idx = blockIdx.x * blockDim.x + threadIdx.x;
    if (idx >= KJ * O_) return;
    int j = idx / O_, o = idx % O_;
    int dt = j / 25 - 2;
    int dy = (j / 5) % 5 - 2;
    int dx = j % 5 - 2;
    double dth = 2.0 * M_PI / (double)O_;
    double th = (double)o * dth;
    double gx = cos(th) * (double)dx - sin(th) * (double)dy;
    double gy = sin(th) * (double)dx + cos(th) * (double)dy;
    dx0t[j * O_ + o] = (int)floor(gx);
    fxt[j * O_ + o] = (float)(gx - floor(gx));
    dy0t[j * O_ + o] = (int)floor(gy);
    fyt[j * O_ + o] = (float)(gy - floor(gy));
    if (o == 0) {
        dot_[j] = dt;
        double a = (double)dt * dth;
        c123[j * 3 + 0] = (float)(cos(a / 2) * dx + sin(a / 2) * dy);
        c123[j * 3 + 1] = (float)(-sin(a / 2) * dx + cos(a / 2) * dy);
        c123[j * 3 + 2] = (float)a;
    }
}

__global__ void k_morph_kern(const float* __restrict__ wm, const float* __restrict__ c123,
                             float* __restrict__ kern, float nu_f, float eh_f) {
    int idx = blockIdx.x * blockDim.x + threadIdx.x;
    if (idx >= C_ * KJ) return;
    int c = idx / KJ, j = idx % KJ;
    float C1 = c123[j * 3 + 0], C2 = c123[j * 3 + 1], C3 = c123[j * 3 + 2];
    float rho2 = wm[c * 3 + 0] * C1 * C1 + wm[c * 3 + 1] * C2 * C2 + wm[c * 3 + 2] * C3 * C3;
    kern[c * KJ + j] = nu_f * powf(rho2, eh_f);
}

// ---------------- morph main: LDS-staged 5-plane tile, unconditional j-loop ----------------
// Tile covers the full read set of a (b,c,o) x 4-row output strip:
//   planes oi = (o+dt)%8 for dt in [-2,2]  -> 5 planes
//   rows   h0-3 .. h0+6                    -> 10 rows
//   cols   -3 .. 196                       -> 200 cols (>=198 needed; OOB = PV)
// Guards happen ONCE at stage time (PV substitution == reference padding),
// the 125-tap loop is fully unconditional. Tap math keeps R0's exact
// per-tap weight products and accumulation order.
template <int DIL>
__global__ __launch_bounds__(192) void k_morph(const float* __restrict__ u,
                                               const int* __restrict__ dy0t,
                                               const int* __restrict__ dx0t,
                                               const float* __restrict__ fyt,
                                               const float* __restrict__ fxt,
                                               const int* __restrict__ dot_,
                                               const float* __restrict__ kern,
                                               float* __restrict__ out) {
    constexpr int TW = 200;            // tile row stride
    constexpr int TR = 10;             // tile rows
    constexpr int TP = TW * TR;        // tile plane = 2000 elements
    int h0 = blockIdx.x * ROWS;
    int bco = blockIdx.y;
    int o = bco % O_;
    int c = (bco / O_) % C_;
    int b = bco / (O_ * C_);

    __shared__ float tile[5 * TP];     // 40000 B
    __shared__ int s_off[KJ];
    __shared__ float s_fy[KJ], s_fx[KJ], s_k[KJ];

    const float PV = DIL ? -BIGF : BIGF;

    // geometry prologue: fuse (plane, dy0, dx0) into one LDS element offset
    for (int t = threadIdx.x; t < KJ; t += blockDim.x) {
        int dt = dot_[t];
        int dy0 = dy0t[t * O_ + o];
        int dx0 = dx0t[t * O_ + o];
        s_off[t] = (dt + 2) * TP + (dy0 + 3) * TW + (dx0 + 3);
        s_fy[t] = fyt[t * O_ + o];
        s_fx[t] = fxt[t * O_ + o];
        s_k[t] = kern[c * KJ + t];
    }
    // stage the 5 source planes (PV outside the H x W interior)
    const float* gbase = u + (size_t)(b * C_ + c) * OHW_;
    for (int idx = threadIdx.x; idx < 5 * TP; idx += blockDim.x) {
        int pl = idx / TP;
        int rem = idx - pl * TP;
        int rr = rem / TW;
        int cc = rem - rr * TW;
        int gy = h0 - 3 + rr;
        int gx = cc - 3;
        int oi = (o + pl + 6) & 7;     // (o + (pl-2)) mod 8
        float v = PV;
        if ((unsigned)gy < (unsigned)H_ && (unsigned)gx < (unsigned)W_)
            v = gbase[oi * HW_ + gy * W_ + gx];
        tile[idx] = v;
    }
    __syncthreads();

    int wI = threadIdx.x;
    float acc[ROWS];
#pragma unroll
    for (int r = 0; r < ROWS; r++) acc[r] = PV;

    for (int j = 0; j < KJ; j++) {
        int a = s_off[j] + wI;
        float fy = s_fy[j], fx = s_fx[j], kk = s_k[j];
        float w00 = (1.0f - fy) * (1.0f - fx);   // (a2,b2)=(0,0)
        float w01 = (1.0f - fy) * fx;            // (0,1)
        float w10 = fy * (1.0f - fx);            // (1,0)
        float w11 = fy * fx;                     // (1,1)
        float c0[ROWS + 1], c1[ROWS + 1];
#pragma unroll
        for (int rr = 0; rr <= ROWS; rr++) {
            c0[rr] = tile[a + rr * TW];
            c1[rr] = tile[a + rr * TW + 1];
        }
#pragma unroll
        for (int r = 0; r < ROWS; r++) {
            float val = w00 * c0[r] + w01 * c1[r] + w10 * c0[r + 1] + w11 * c1[r + 1];
            if (DIL) acc[r] = fmaxf(acc[r], val - kk);
            else     acc[r] = fminf(acc[r], val + kk);
        }
    }
    float* op = out + (size_t)bco * HW_ + (size_t)h0 * W_ + wI;
#pragma unroll
    for (int r = 0; r < ROWS; r++) op[r * W_] = acc[r];
}

// ---------------- channel linear: z[b,d,o,h,w] = sum_c lin[d,c]*cat(d,e) ----------------
__global__ __launch_bounds__(256) void k_linear(const float* __restrict__ dbuf,
                                                const float* __restrict__ ebuf,
                                                const float* __restrict__ lin,
                                                float* __restrict__ out) {
    __shared__ float lsm[C_ * 2 * C_];
    for (int t = threadIdx.x; t < C_ * 2 * C_; t += blockDim.x) lsm[t] = lin[t];
    __syncthreads();
    int idx = blockIdx.x * blockDim.x + threadIdx.x;   // over B*O*H*W
    if (idx >= B_ * OHW_) return;
    int pos = idx % OHW_;
    int b = idx / OHW_;
    const float* dp = dbuf + (size_t)b * COHW_ + pos;
    const float* ep = ebuf + (size_t)b * COHW_ + pos;
    float vin[2 * C_];
    for (int c2 = 0; c2 < C_; c2++) {
        vin[c2] = dp[(size_t)c2 * OHW_];
        vin[C_ + c2] = ep[(size_t)c2 * OHW_];
    }
    for (int dch = 0; dch < C_; dch++) {
        float s = 0.f;
        for (int c2 = 0; c2 < 2 * C_; c2++) s += lsm[dch * 2 * C_ + c2] * vin[c2];
        out[(size_t)b * COHW_ + (size_t)dch * OHW_ + pos] = s;
    }
}

// ---------------- final: max over O, project, sigmoid ----------------
__global__ __launch_bounds__(256) void k_final(const float* __restrict__ u,
                                               const float* __restrict__ fw,
                                               float* __restrict__ out) {
    int idx = blockIdx.x * blockDim.x + threadIdx.x;   // B*H*W
    if (idx >= B_ * HW_) return;
    int pos = idx % HW_;
    int b = idx / HW_;
    const float* up = u + (size_t)b * COHW_ + pos;
    float y = 0.f;
    for (int c2 = 0; c2 < C_; c2++) {
        float m = up[(size_t)(c2 * O_) * HW_];
        for (int o2 = 1; o2 < O_; o2++) m = fmaxf(m, up[(size_t)(c2 * O_ + o2) * HW_]);
        y += fw[c2] * m;
    }
    out[idx] = 1.0f / (1.0f + expf(-y));
}

// ---------------- host orchestration ----------------
extern "C" void kernel_launch(void* const* d_in, const int* in_sizes, int n_in,
                              void* d_out, int out_size, void* d_ws, size_t ws_size,
                              hipStream_t stream) {
    const float* x          = (const float*)d_in[0];
    const float* lift_w     = (const float*)d_in[1];
    const float* lift_gamma = (const float*)d_in[2];
    const float* lift_beta  = (const float*)d_in[3];
    const float* pde_g      = (const float*)d_in[4];
    const float* pde_metric = (const float*)d_in[5];
    const float* pde_lin    = (const float*)d_in[6];
    const float* pde_gamma  = (const float*)d_in[7];
    const float* pde_beta   = (const float*)d_in[8];
    const float* final_w    = (const float*)d_in[9];
    float* out = (float*)d_out;

    float* ws   = (float*)d_ws;
    float* bufA = ws;                         // u
    float* bufB = ws + (size_t)NTOT;          // scratch (convect out / z)
    float* bufC = ws + 2 * (size_t)NTOT;      // d
    float* wr   = ws + 3 * (size_t)NTOT;      // 18816
    float* fyt  = wr + 18816;                 // 1000
    float* fxt  = fyt + 1000;                 // 1000
    float* c123 = fxt + 1000;                 // 375
    float* kern = c123 + 375;                 // 2000
    float* sums = kern + 2000;                // 32
    int* dy0t = (int*)(sums + 32);            // 1000
    int* dx0t = dy0t + 1000;                  // 1000
    int* dot_ = dx0t + 1000;                  // 125

    const double ALPHA = 0.65;
    const double EXPO = 2.0 * ALPHA / (2.0 * ALPHA - 1.0);
    const double NU = (2.0 * ALPHA - 1.0) * pow(2.0 * ALPHA, -EXPO);
    const float nu_f = (float)NU;
    const float eh_f = (float)(EXPO / 2.0);

    dim3 rowGrid(H_, B_ * C_ * O_);
    dim3 morphGrid(H_ / ROWS, B_ * C_ * O_);

    k_lift_weights<<<(C_ * O_ * 3 * 49 + 255) / 256, 256, 0, stream>>>(lift_w, wr);
    k_morph_geo<<<(KJ * O_ + 255) / 256, 256, 0, stream>>>(dy0t, dx0t, fyt, fxt, dot_, c123);
    k_lift_conv<<<rowGrid, 192, 0, stream>>>(x, wr, bufA);

    hipMemsetAsync(sums, 0, 2 * C_ * sizeof(float), stream);
    k_bn_reduce<<<B_ * C_ * O_, 256, 0, stream>>>(bufA, sums);
    k_bn_apply<<<(NTOT + 255) / 256, 256, 0, stream>>>(bufA, sums, lift_gamma, lift_beta);

    for (int l = 0; l < NL_; l++) {
        const float* g0 = pde_g + (size_t)(l * 2 + 0) * C_ * 3;
        const float* g1 = pde_g + (size_t)(l * 2 + 1) * C_ * 3;
        const float* m0 = pde_metric + (size_t)(l * 2 + 0) * C_ * 3;
        const float* m1 = pde_metric + (size_t)(l * 2 + 1) * C_ * 3;
        const float* lin = pde_lin + (size_t)l * C_ * 2 * C_;
        const float* ga = pde_gamma + l * C_;
        const float* be = pde_beta + l * C_;

        // d = morph_dilate(convect(u,g0))
        k_convect<<<rowGrid, 192, 0, stream>>>(bufA, g0, bufB);
        k_morph_kern<<<(C_ * KJ + 255) / 256, 256, 0, stream>>>(m0, c123, kern, nu_f, eh_f);
        k_morph<1><<<morphGrid, 192, 0, stream>>>(bufB, dy0t, dx0t, fyt, fxt, dot_, kern, bufC);
        // e = morph_erode(convect(u,g1))  -- e overwrites u (dead after this convect)
        k_convect<<<rowGrid, 192, 0, stream>>>(bufA, g1, bufB);
        k_morph_kern<<<(C_ * KJ + 255) / 256, 256, 0, stream>>>(m1, c123, kern, nu_f, eh_f);
        k_morph<0><<<morphGrid, 192, 0, stream>>>(bufB, dy0t, dx0t, fyt, fxt, dot_, kern, bufA);
        // z = lin * cat(d,e) -> bufB ; bn(z)
        k_linear<<<(B_ * OHW_ + 255) / 256, 256, 0, stream>>>(bufC, bufA, lin, bufB);
        hipMemsetAsync(sums, 0, 2 * C_ * sizeof(float), stream);
        k_bn_reduce<<<B_ * C_ * O_, 256, 0, stream>>>(bufB, sums);
        k_bn_apply<<<(NTOT + 255) / 256, 256, 0, stream>>>(bufB, sums, ga, be);
        // rotate: new u = bufB
        float* t = bufA; bufA = bufB; bufB = t;
    }

    k_final<<<(B_ * HW_ + 255) / 256, 256, 0, stream>>>(bufA, final_w, out);
}